// Round 2
// baseline (125.730 us; speedup 1.0000x reference)
//
#include <hip/hip_runtime.h>
#include <math.h>

#define B_   8
#define T_   4096
#define D_   1024
#define LCH  64               // chunk length along T
#define CCH  (T_/LCH)         // 64 chunks
#define BD   (B_*D_)          // 8192
#define EPS_ 1e-5f

__device__ __forceinline__ float gelu_f(float x) {
    const float c = 0.7978845608028654f;  // sqrt(2/pi)
    float x3 = x * x * x;
    float y  = c * (x + 0.044715f * x3);
    float e  = __expf(2.0f * y);
    float th = 1.0f - 2.0f / (1.0f + e);
    return 0.5f * x * (1.0f + th);
}

__device__ __forceinline__ float sigmoid_f(float z) {
    return 1.0f / (1.0f + __expf(-z));
}

// K1: per (b, d, chunk) compute S = sum_i d^(L-1-i) * (1-d) * |gelu(x_t)|
__global__ __launch_bounds__(1024) void k1_chunksum(
        const float* __restrict__ x,
        const float* __restrict__ logit_d_ca,
        float* __restrict__ S) {
    const int c = blockIdx.x, b = blockIdx.y, d = threadIdx.x;
    const float dca  = sigmoid_f(logit_d_ca[0]);
    const float omd  = 1.0f - dca;
    const float* xp = x + ((size_t)b * T_ + (size_t)c * LCH) * D_ + d;
    float s = 0.0f;
    #pragma unroll 4
    for (int i = 0; i < LCH; ++i) {
        float f = fabsf(gelu_f(xp[(size_t)i * D_]));
        s = dca * s + omd * f;
    }
    S[(size_t)c * BD + (size_t)b * D_ + d] = s;
}

// K2: sequential chain over chunks; converts S[c] (chunk sums) into
// Ca_start[c] (Ca value at the beginning of chunk c), in place.
__global__ __launch_bounds__(256) void k2_chain(
        const float* __restrict__ logit_d_ca,
        const float* __restrict__ ema,
        float* __restrict__ S) {
    const int idx = blockIdx.x * 256 + threadIdx.x;  // = b*D + d
    if (idx >= BD) return;
    const int d = idx & (D_ - 1);
    const float dca = sigmoid_f(logit_d_ca[0]);
    float dL = dca;
    #pragma unroll
    for (int k = 0; k < 6; ++k) dL *= dL;  // dca^64
    float Ca = ema[d];
    #pragma unroll 4
    for (int c = 0; c < CCH; ++c) {
        float s = S[(size_t)c * BD + idx];
        S[(size_t)c * BD + idx] = Ca;   // Ca at start of chunk c
        Ca = dL * Ca + s;               // Ca at start of chunk c+1
    }
}

// K3: per (b, chunk). Phase A: scan gates, per-wave shfl partials into LDS
// (no barrier). One barrier. 1024 threads reduce 64x16 partials -> rinv[i].
// One barrier. Phase B: rescan (x is cache-hot), write output.
__global__ __launch_bounds__(1024) void k3_fused(
        const float* __restrict__ x,
        const float* __restrict__ log_beta_raw,
        const float* __restrict__ logit_d_ca,
        const float* __restrict__ CaS,
        float* __restrict__ out) {
    const int c = blockIdx.x, b = blockIdx.y, d = threadIdx.x;
    const int wave = threadIdx.x >> 6, lane = threadIdx.x & 63;
    __shared__ float wpart[LCH][16];   // [i][wave] : stride 16 -> no conflicts
    __shared__ float rinv[LCH];

    const float lbr  = log_beta_raw[0];
    const float beta = (lbr > 20.0f) ? lbr : log1pf(__expf(lbr));
    const float dca  = sigmoid_f(logit_d_ca[0]);
    const float omd  = 1.0f - dca;

    const float Ca0 = CaS[(size_t)c * BD + (size_t)b * D_ + d];
    const size_t base = ((size_t)b * T_ + (size_t)c * LCH) * D_ + d;

    // ---- Phase A: gates + wave partial sums (no barriers) ----
    float Ca = Ca0;
    #pragma unroll 4
    for (int i = 0; i < LCH; ++i) {
        float xv = x[base + (size_t)i * D_];
        float o    = gelu_f(xv);
        float gate = 1.0f / (1.0f + beta * Ca);
        Ca = dca * Ca + omd * fabsf(o);
        float g = gate;
        #pragma unroll
        for (int m = 32; m >= 1; m >>= 1) g += __shfl_xor(g, m, 64);
        if (lane == 0) wpart[i][wave] = g;
    }
    __syncthreads();

    // ---- Reduce: one partial per thread; sum within 16-lane groups ----
    {
        float v = wpart[threadIdx.x >> 4][threadIdx.x & 15];
        v += __shfl_xor(v, 1, 64);
        v += __shfl_xor(v, 2, 64);
        v += __shfl_xor(v, 4, 64);
        v += __shfl_xor(v, 8, 64);
        if ((threadIdx.x & 15) == 0)
            rinv[threadIdx.x >> 4] = 1.0f / (v * (1.0f / (float)D_) + EPS_);
    }
    __syncthreads();

    // ---- Phase B: rescan (cache-hot) and write output ----
    Ca = Ca0;
    #pragma unroll 4
    for (int i = 0; i < LCH; ++i) {
        float xv = x[base + (size_t)i * D_];
        float o    = gelu_f(xv);
        float gate = 1.0f / (1.0f + beta * Ca);
        Ca = dca * Ca + omd * fabsf(o);
        out[base + (size_t)i * D_] = o * gate * rinv[i];
    }
}

extern "C" void kernel_launch(void* const* d_in, const int* in_sizes, int n_in,
                              void* d_out, int out_size, void* d_ws, size_t ws_size,
                              hipStream_t stream) {
    const float* x    = (const float*)d_in[0];
    const float* lbr  = (const float*)d_in[1];
    const float* ldc  = (const float*)d_in[2];
    // d_in[3] (logit_decay) is unused by the steady-state reference path
    const float* ema  = (const float*)d_in[4];
    float* S   = (float*)d_ws;   // CCH * B * D floats = 2 MiB
    float* out = (float*)d_out;

    dim3 grid(CCH, B_);
    k1_chunksum<<<grid, 1024, 0, stream>>>(x, ldc, S);
    k2_chain<<<BD / 256, 256, 0, stream>>>(ldc, ema, S);
    k3_fused<<<grid, 1024, 0, stream>>>(x, lbr, ldc, S, out);
}

// Round 3
// 86.654 us; speedup vs baseline: 1.4509x; 1.4509x over previous
//
#include <hip/hip_runtime.h>
#include <math.h>

#define B_   8
#define T_   4096
#define D_   1024
#define LCH  32               // chunk length along T (k3 block = one chunk)
#define CCH  (T_/LCH)         // 128 chunks
#define BD   (B_*D_)          // 8192
#define EPS_ 1e-5f

__device__ __forceinline__ float rcp_f(float x) { return __builtin_amdgcn_rcpf(x); }

// 0.5x(1+tanh(c(x+0.044715x^3))) = x - x*r,  r = 1/(1+exp(2c(x+0.044715x^3)))
__device__ __forceinline__ float gelu_fast(float x) {
    const float two_c = 1.5957691216057308f;   // 2*sqrt(2/pi)
    float x2 = x * x;
    float y2 = two_c * x * fmaf(0.044715f, x2, 1.0f);
    float e  = __expf(y2);                      // inf/0 at tails -> exact limits
    float r  = rcp_f(1.0f + e);
    return fmaf(-x, r, x);
}

__device__ __forceinline__ float sigmoid_f(float z) {
    return rcp_f(1.0f + __expf(-z));
}

// K1: per (b, 4d, chunk) decay-weighted chunk sums of |gelu(x)|
__global__ __launch_bounds__(256) void k1_chunksum(
        const float* __restrict__ x,
        const float* __restrict__ logit_d_ca,
        float* __restrict__ S) {
    const int c = blockIdx.x, b = blockIdx.y;
    const int d0 = threadIdx.x * 4;
    const float dca = sigmoid_f(logit_d_ca[0]);
    const float omd = 1.0f - dca;
    const float4* xp = (const float4*)(x + ((size_t)b*T_ + (size_t)c*LCH)*D_ + d0);
    float4 s = {0.f, 0.f, 0.f, 0.f};
    #pragma unroll 8
    for (int i = 0; i < LCH; ++i) {
        float4 v = xp[(size_t)i * (D_/4)];
        s.x = fmaf(dca, s.x, omd * fabsf(gelu_fast(v.x)));
        s.y = fmaf(dca, s.y, omd * fabsf(gelu_fast(v.y)));
        s.z = fmaf(dca, s.z, omd * fabsf(gelu_fast(v.z)));
        s.w = fmaf(dca, s.w, omd * fabsf(gelu_fast(v.w)));
    }
    *(float4*)(S + (size_t)c*BD + (size_t)b*D_ + d0) = s;
}

// K2: sequential chain over chunks; S[c] (chunk sums) -> Ca at chunk starts.
__global__ __launch_bounds__(256) void k2_chain(
        const float* __restrict__ logit_d_ca,
        const float* __restrict__ ema,
        float* __restrict__ S) {
    const int idx = blockIdx.x * 256 + threadIdx.x;  // = b*D + d
    const int d = idx & (D_ - 1);
    const float dca = sigmoid_f(logit_d_ca[0]);
    float dL = dca;
    #pragma unroll
    for (int k = 0; k < 5; ++k) dL *= dL;            // dca^32
    float Ca = ema[d];
    #pragma unroll 8
    for (int c = 0; c < CCH; ++c) {
        float s = S[(size_t)c * BD + idx];
        S[(size_t)c * BD + idx] = Ca;                // Ca at start of chunk c
        Ca = fmaf(dL, Ca, s);                        // Ca at start of chunk c+1
    }
}

// K3: per (b, chunk). Phase A: scan, save o*gate in regs, gate-pair sums to
// LDS (no shfl). One barrier. 512-thread reduce -> rinv per timestep (stored
// in gp[i][0]). One barrier. Phase B: scale saved values and store.
__global__ __launch_bounds__(512, 4) void k3_fused(
        const float* __restrict__ x,
        const float* __restrict__ log_beta_raw,
        const float* __restrict__ logit_d_ca,
        const float* __restrict__ CaS,
        float* __restrict__ out) {
    const int c = blockIdx.x, b = blockIdx.y;
    const int tid = threadIdx.x;
    __shared__ float gp[LCH][512];                   // 64 KiB

    const float lbr  = log_beta_raw[0];
    const float beta = (lbr > 20.0f) ? lbr : log1pf(__expf(lbr));
    const float dca  = sigmoid_f(logit_d_ca[0]);
    const float omd  = 1.0f - dca;

    const float2 ca2 = ((const float2*)(CaS + (size_t)c*BD + (size_t)b*D_))[tid];
    float Ca0 = ca2.x, Ca1 = ca2.y;

    const float2* xp = (const float2*)(x   + ((size_t)b*T_ + (size_t)c*LCH)*D_) + tid;
    float2*       op = (float2*)      (out + ((size_t)b*T_ + (size_t)c*LCH)*D_) + tid;

    float2 sv[LCH];                                  // o*gate, statically indexed
    #pragma unroll
    for (int i = 0; i < LCH; ++i) {
        float2 v  = xp[i * (D_/2)];
        float o0  = gelu_fast(v.x);
        float o1  = gelu_fast(v.y);
        float g0  = rcp_f(fmaf(beta, Ca0, 1.0f));
        float g1  = rcp_f(fmaf(beta, Ca1, 1.0f));
        Ca0 = fmaf(dca, Ca0, omd * fabsf(o0));
        Ca1 = fmaf(dca, Ca1, omd * fabsf(o1));
        sv[i].x = o0 * g0;
        sv[i].y = o1 * g1;
        gp[i][tid] = g0 + g1;
    }
    __syncthreads();

    {   // one timestep per 16-thread group; strided reads are conflict-free
        const int i = tid >> 4, t16 = tid & 15;
        float v = 0.f;
        #pragma unroll
        for (int j = 0; j < 32; ++j) v += gp[i][t16 + (j << 4)];
        v += __shfl_xor(v, 1, 64);
        v += __shfl_xor(v, 2, 64);
        v += __shfl_xor(v, 4, 64);
        v += __shfl_xor(v, 8, 64);
        if (t16 == 0)                                 // only this thread touches [i][0] again
            gp[i][0] = rcp_f(fmaf(v, 1.0f/(float)D_, EPS_));
    }
    __syncthreads();

    #pragma unroll
    for (int i = 0; i < LCH; ++i) {
        float ri = gp[i][0];                          // uniform broadcast read
        float2 w; w.x = sv[i].x * ri; w.y = sv[i].y * ri;
        op[i * (D_/2)] = w;
    }
}

extern "C" void kernel_launch(void* const* d_in, const int* in_sizes, int n_in,
                              void* d_out, int out_size, void* d_ws, size_t ws_size,
                              hipStream_t stream) {
    const float* x    = (const float*)d_in[0];
    const float* lbr  = (const float*)d_in[1];
    const float* ldc  = (const float*)d_in[2];
    // d_in[3] (logit_decay) unused by the steady-state reference path
    const float* ema  = (const float*)d_in[4];
    float* S   = (float*)d_ws;   // CCH * B * D floats = 4 MiB
    float* out = (float*)d_out;

    dim3 grid(CCH, B_);
    k1_chunksum<<<grid, 256, 0, stream>>>(x, ldc, S);
    k2_chain<<<BD / 256, 256, 0, stream>>>(ldc, ema, S);
    k3_fused<<<grid, 512, 0, stream>>>(x, lbr, ldc, S, out);
}

// Round 4
// 85.185 us; speedup vs baseline: 1.4760x; 1.0172x over previous
//
#include <hip/hip_runtime.h>
#include <math.h>

#define B_   8
#define T_   4096
#define D_   1024
#define LCH  32               // chunk length along T (k3 block = one chunk)
#define CCH  (T_/LCH)         // 128 chunks
#define BD   (B_*D_)          // 8192
#define EPS_ 1e-5f

typedef float vf2 __attribute__((ext_vector_type(2)));

__device__ __forceinline__ float rcp_f(float x) { return __builtin_amdgcn_rcpf(x); }

// 0.5x(1+tanh(c(x+0.044715x^3))) = x - x*r,  r = 1/(1+exp(2c(x+0.044715x^3)))
__device__ __forceinline__ float gelu_fast(float x) {
    const float two_c = 1.5957691216057308f;   // 2*sqrt(2/pi)
    float x2 = x * x;
    float y2 = two_c * x * fmaf(0.044715f, x2, 1.0f);
    float e  = __expf(y2);                      // inf/0 at tails -> exact limits
    float r  = rcp_f(1.0f + e);
    return fmaf(-x, r, x);
}

__device__ __forceinline__ float sigmoid_f(float z) {
    return rcp_f(1.0f + __expf(-z));
}

// K1: per (b, 4d, chunk) decay-weighted chunk sums of |gelu(x)|
__global__ __launch_bounds__(256) void k1_chunksum(
        const float* __restrict__ x,
        const float* __restrict__ logit_d_ca,
        float* __restrict__ S) {
    const int c = blockIdx.x, b = blockIdx.y;
    const int d0 = threadIdx.x * 4;
    const float dca = sigmoid_f(logit_d_ca[0]);
    const float omd = 1.0f - dca;
    const float4* xp = (const float4*)(x + ((size_t)b*T_ + (size_t)c*LCH)*D_ + d0);
    float4 s = {0.f, 0.f, 0.f, 0.f};
    #pragma unroll 8
    for (int i = 0; i < LCH; ++i) {
        float4 v = xp[(size_t)i * (D_/4)];
        s.x = fmaf(dca, s.x, omd * fabsf(gelu_fast(v.x)));
        s.y = fmaf(dca, s.y, omd * fabsf(gelu_fast(v.y)));
        s.z = fmaf(dca, s.z, omd * fabsf(gelu_fast(v.z)));
        s.w = fmaf(dca, s.w, omd * fabsf(gelu_fast(v.w)));
    }
    *(float4*)(S + (size_t)c*BD + (size_t)b*D_ + d0) = s;
}

// K2: sequential chain over chunks; S[c] (chunk sums) -> Ca at chunk starts.
__global__ __launch_bounds__(256) void k2_chain(
        const float* __restrict__ logit_d_ca,
        const float* __restrict__ ema,
        float* __restrict__ S) {
    const int idx = blockIdx.x * 256 + threadIdx.x;  // = b*D + d
    const int d = idx & (D_ - 1);
    const float dca = sigmoid_f(logit_d_ca[0]);
    float dL = dca;
    #pragma unroll
    for (int k = 0; k < 5; ++k) dL *= dL;            // dca^32
    float Ca = ema[d];
    #pragma unroll 8
    for (int c = 0; c < CCH; ++c) {
        float s = S[(size_t)c * BD + idx];
        S[(size_t)c * BD + idx] = Ca;                // Ca at start of chunk c
        Ca = fmaf(dL, Ca, s);                        // Ca at start of chunk c+1
    }
}

// K3: per (b, chunk). Phase A: scan, save o*gate in regs, gate-pair sums to
// LDS. One barrier. 512-thread reduce -> rinv per timestep (gp[i][0]).
// One barrier. Phase B: scale saved values, NON-TEMPORAL store (keep x in L3).
__global__ __launch_bounds__(512, 4) void k3_fused(
        const float* __restrict__ x,
        const float* __restrict__ log_beta_raw,
        const float* __restrict__ logit_d_ca,
        const float* __restrict__ CaS,
        float* __restrict__ out) {
    const int c = blockIdx.x, b = blockIdx.y;
    const int tid = threadIdx.x;
    __shared__ float gp[LCH][512];                   // 64 KiB

    const float lbr  = log_beta_raw[0];
    const float beta = (lbr > 20.0f) ? lbr : log1pf(__expf(lbr));
    const float dca  = sigmoid_f(logit_d_ca[0]);
    const float omd  = 1.0f - dca;

    const vf2 ca2 = ((const vf2*)(CaS + (size_t)c*BD + (size_t)b*D_))[tid];
    float Ca0 = ca2.x, Ca1 = ca2.y;

    const vf2* xp = (const vf2*)(x   + ((size_t)b*T_ + (size_t)c*LCH)*D_) + tid;
    vf2*       op = (vf2*)      (out + ((size_t)b*T_ + (size_t)c*LCH)*D_) + tid;

    vf2 sv[LCH];                                     // o*gate, statically indexed
    #pragma unroll
    for (int i = 0; i < LCH; ++i) {
        vf2 v     = xp[i * (D_/2)];
        float o0  = gelu_fast(v.x);
        float o1  = gelu_fast(v.y);
        float g0  = rcp_f(fmaf(beta, Ca0, 1.0f));
        float g1  = rcp_f(fmaf(beta, Ca1, 1.0f));
        Ca0 = fmaf(dca, Ca0, omd * fabsf(o0));
        Ca1 = fmaf(dca, Ca1, omd * fabsf(o1));
        sv[i].x = o0 * g0;
        sv[i].y = o1 * g1;
        gp[i][tid] = g0 + g1;
    }
    __syncthreads();

    {   // one timestep per 16-thread group
        const int i = tid >> 4, t16 = tid & 15;
        float v = 0.f;
        #pragma unroll
        for (int j = 0; j < 32; ++j) v += gp[i][t16 + (j << 4)];
        v += __shfl_xor(v, 1, 64);
        v += __shfl_xor(v, 2, 64);
        v += __shfl_xor(v, 4, 64);
        v += __shfl_xor(v, 8, 64);
        if (t16 == 0)                                 // only this thread touches [i][0] again
            gp[i][0] = rcp_f(fmaf(v, 1.0f/(float)D_, EPS_));
    }
    __syncthreads();

    #pragma unroll
    for (int i = 0; i < LCH; ++i) {
        float ri = gp[i][0];                          // uniform broadcast read
        vf2 w; w.x = sv[i].x * ri; w.y = sv[i].y * ri;
        __builtin_nontemporal_store(w, op + i * (D_/2));
    }
}

extern "C" void kernel_launch(void* const* d_in, const int* in_sizes, int n_in,
                              void* d_out, int out_size, void* d_ws, size_t ws_size,
                              hipStream_t stream) {
    const float* x    = (const float*)d_in[0];
    const float* lbr  = (const float*)d_in[1];
    const float* ldc  = (const float*)d_in[2];
    // d_in[3] (logit_decay) unused by the steady-state reference path
    const float* ema  = (const float*)d_in[4];
    float* S   = (float*)d_ws;   // CCH * B * D floats = 4 MiB
    float* out = (float*)d_out;

    dim3 grid(CCH, B_);
    k1_chunksum<<<grid, 256, 0, stream>>>(x, ldc, S);
    k2_chain<<<BD / 256, 256, 0, stream>>>(ldc, ema, S);
    k3_fused<<<grid, 512, 0, stream>>>(x, lbr, ldc, S, out);
}

// Round 5
// 80.732 us; speedup vs baseline: 1.5574x; 1.0552x over previous
//
#include <hip/hip_runtime.h>
#include <math.h>

#define B_   8
#define T_   4096
#define D_   1024
#define LCH  32               // chunk length along T (k3 block = one chunk)
#define LCHH 16               // half-chunk (k3 inner phase)
#define CCH  (T_/LCH)         // 128 chunks
#define BD   (B_*D_)          // 8192
#define EPS_ 1e-5f

typedef float vf2 __attribute__((ext_vector_type(2)));

__device__ __forceinline__ float rcp_f(float x) { return __builtin_amdgcn_rcpf(x); }

// 0.5x(1+tanh(c(x+0.044715x^3))) = x - x*r,  r = 1/(1+exp(2c(x+0.044715x^3)))
__device__ __forceinline__ float gelu_fast(float x) {
    const float two_c = 1.5957691216057308f;   // 2*sqrt(2/pi)
    float x2 = x * x;
    float y2 = two_c * x * fmaf(0.044715f, x2, 1.0f);
    float e  = __expf(y2);                      // inf/0 at tails -> exact limits
    float r  = rcp_f(1.0f + e);
    return fmaf(-x, r, x);
}

__device__ __forceinline__ float sigmoid_f(float z) {
    return rcp_f(1.0f + __expf(-z));
}

// K1: per (b, 4d, chunk) decay-weighted chunk sums of |gelu(x)|
__global__ __launch_bounds__(256) void k1_chunksum(
        const float* __restrict__ x,
        const float* __restrict__ logit_d_ca,
        float* __restrict__ S) {
    const int c = blockIdx.x, b = blockIdx.y;
    const int d0 = threadIdx.x * 4;
    const float dca = sigmoid_f(logit_d_ca[0]);
    const float omd = 1.0f - dca;
    const float4* xp = (const float4*)(x + ((size_t)b*T_ + (size_t)c*LCH)*D_ + d0);
    float4 s = {0.f, 0.f, 0.f, 0.f};
    #pragma unroll 8
    for (int i = 0; i < LCH; ++i) {
        float4 v = xp[(size_t)i * (D_/4)];
        s.x = fmaf(dca, s.x, omd * fabsf(gelu_fast(v.x)));
        s.y = fmaf(dca, s.y, omd * fabsf(gelu_fast(v.y)));
        s.z = fmaf(dca, s.z, omd * fabsf(gelu_fast(v.z)));
        s.w = fmaf(dca, s.w, omd * fabsf(gelu_fast(v.w)));
    }
    *(float4*)(S + (size_t)c*BD + (size_t)b*D_ + d0) = s;
}

// K2: sequential chain over chunks; S[c] (chunk sums) -> Ca at chunk starts.
__global__ __launch_bounds__(256) void k2_chain(
        const float* __restrict__ logit_d_ca,
        const float* __restrict__ ema,
        float* __restrict__ S) {
    const int idx = blockIdx.x * 256 + threadIdx.x;  // = b*D + d
    const int d = idx & (D_ - 1);
    const float dca = sigmoid_f(logit_d_ca[0]);
    float dL = dca;
    #pragma unroll
    for (int k = 0; k < 5; ++k) dL *= dL;            // dca^32
    float Ca = ema[d];
    #pragma unroll 8
    for (int c = 0; c < CCH; ++c) {
        float s = S[(size_t)c * BD + idx];
        S[(size_t)c * BD + idx] = Ca;                // Ca at start of chunk c
        Ca = fmaf(dL, Ca, s);                        // Ca at start of chunk c+1
    }
}

// K3: per (b, chunk). Two half-chunks of 16 steps, Ca carried in registers.
// Per half: scan (sv regs + gate-pair sums to LDS), barrier, 512-thread
// reduce -> rinv[16], barrier, scaled NT store. Hazards: gp reads (reduce)
// end before sync2, gp writes (next scan) start after sync2; rinv reads
// (out) end before next sync1, rinv writes (next reduce) after it. 4 syncs.
__global__ __launch_bounds__(512, 4) void k3_fused(
        const float* __restrict__ x,
        const float* __restrict__ log_beta_raw,
        const float* __restrict__ logit_d_ca,
        const float* __restrict__ CaS,
        float* __restrict__ out) {
    const int c = blockIdx.x, b = blockIdx.y;
    const int tid = threadIdx.x;
    __shared__ float gp[LCHH][512];                  // 32 KiB
    __shared__ float rinv[LCHH];

    const float lbr  = log_beta_raw[0];
    const float beta = (lbr > 20.0f) ? lbr : log1pf(__expf(lbr));
    const float dca  = sigmoid_f(logit_d_ca[0]);
    const float omd  = 1.0f - dca;

    const vf2 ca2 = ((const vf2*)(CaS + (size_t)c*BD + (size_t)b*D_))[tid];
    float Ca0 = ca2.x, Ca1 = ca2.y;

    const vf2* xp = (const vf2*)(x   + ((size_t)b*T_ + (size_t)c*LCH)*D_) + tid;
    vf2*       op = (vf2*)      (out + ((size_t)b*T_ + (size_t)c*LCH)*D_) + tid;

    vf2 sv[LCHH];                                    // o*gate, statically indexed

    #pragma unroll
    for (int h = 0; h < 2; ++h) {
        const int bi = h * LCHH;

        #pragma unroll
        for (int i = 0; i < LCHH; ++i) {
            vf2 v     = __builtin_nontemporal_load(xp + (size_t)(bi + i) * (D_/2));
            float o0  = gelu_fast(v.x);
            float o1  = gelu_fast(v.y);
            float g0  = rcp_f(fmaf(beta, Ca0, 1.0f));
            float g1  = rcp_f(fmaf(beta, Ca1, 1.0f));
            Ca0 = fmaf(dca, Ca0, omd * fabsf(o0));
            Ca1 = fmaf(dca, Ca1, omd * fabsf(o1));
            sv[i].x = o0 * g0;
            sv[i].y = o1 * g1;
            gp[i][tid] = g0 + g1;
        }
        __syncthreads();

        {   // one timestep per 32-thread group; banks: 2 lanes/bank = free
            const int i = tid >> 5, t32 = tid & 31;
            float v = 0.f;
            #pragma unroll
            for (int j = 0; j < LCHH; ++j) v += gp[i][t32 + (j << 5)];
            v += __shfl_xor(v, 1, 64);
            v += __shfl_xor(v, 2, 64);
            v += __shfl_xor(v, 4, 64);
            v += __shfl_xor(v, 8, 64);
            v += __shfl_xor(v, 16, 64);
            if (t32 == 0)
                rinv[i] = rcp_f(fmaf(v, 1.0f/(float)D_, EPS_));
        }
        __syncthreads();

        #pragma unroll
        for (int i = 0; i < LCHH; ++i) {
            float ri = rinv[i];
            vf2 w; w.x = sv[i].x * ri; w.y = sv[i].y * ri;
            __builtin_nontemporal_store(w, op + (size_t)(bi + i) * (D_/2));
        }
    }
}

extern "C" void kernel_launch(void* const* d_in, const int* in_sizes, int n_in,
                              void* d_out, int out_size, void* d_ws, size_t ws_size,
                              hipStream_t stream) {
    const float* x    = (const float*)d_in[0];
    const float* lbr  = (const float*)d_in[1];
    const float* ldc  = (const float*)d_in[2];
    // d_in[3] (logit_decay) unused by the steady-state reference path
    const float* ema  = (const float*)d_in[4];
    float* S   = (float*)d_ws;   // CCH * B * D floats = 4 MiB
    float* out = (float*)d_out;

    dim3 grid(CCH, B_);
    k1_chunksum<<<grid, 256, 0, stream>>>(x, ldc, S);
    k2_chain<<<BD / 256, 256, 0, stream>>>(ldc, ema, S);
    k3_fused<<<grid, 512, 0, stream>>>(x, lbr, ldc, S, out);
}